// Round 2
// 393.269 us; speedup vs baseline: 1.0062x; 1.0062x over previous
//
#include <hip/hip_runtime.h>

typedef unsigned short u16;
typedef unsigned int u32;
typedef short bf16x8 __attribute__((ext_vector_type(8)));
typedef float f32x4  __attribute__((ext_vector_type(4)));

#define NN 64
#define DD 256
#define LL 4096
#define KK 64
#define CHUNK 512
#define SUB 32        // columns per substep
#define NSTEP 16      // CHUNK / SUB
#define NCH 8         // chunks per image
#define SSZ (KK*DD)   // 16384
// LDS strides in u16 elements; byte stride must be %16==0 for b128 access
#define XLD_S 264     // x_ld row stride (256 d + pad)
#define XDL_S 40      // x_dl row stride (32 cols + pad)
#define AKL_S 40      // akl row stride (32 cols + pad)

__device__ __forceinline__ u16 f2bf(float f) {
  union { float f; u32 i; } v; v.f = f;
  return (u16)((v.i + 0x8000u) >> 16);   // round-half-up (quantization only)
}

// LDS-only barrier: wait LDS ops, sync, but leave global loads (vmcnt) in
// flight across the barrier (CK block_sync_lds idiom).
__device__ __forceinline__ void barrier_lds() {
  asm volatile("s_waitcnt lgkmcnt(0)\n\ts_barrier" ::: "memory");
}

__global__ void zero_ws_kernel(float* __restrict__ p, int n4) {
  int i = blockIdx.x * 256 + threadIdx.x;
  if (i < n4) ((f32x4*)p)[i] = (f32x4){0.f, 0.f, 0.f, 0.f};
}

// ---------------------------------------------------------------------------
// Main fused kernel, register-streaming pipeline, 2 barriers per substep.
//   S[k,d] = sum_l (softmax[k,l]*rno[l]) * x[d,l],  A[k] = sum_l softmax[k,l]
// Scale-split: akl stores bf16(e*rno) (written pre-B2, cross-wave, protected
// by B2); the softmax denominator rs[l] is folded into the wave-PRIVATE
// x_dl = bf16(x*rs), written post-B2 and consumed by the same wave's GEMM2
// after an lgkmcnt wait only. This removes barriers B3 and B4 entirely:
//   stage x_ld+pnw -> B1 -> GEMM1 -> p1 (e, wsum, akl=e*rno) -> B2 ->
//   rs, regAk, x_dl=x*rs -> lgkmcnt -> GEMM2 -> (next substep stage).
// Hazards: B2 guarantees all waves finished GEMM1/p1 (x_ld, pnw reads done)
// before any wave's next-substep stage writes them; next-B1 guarantees all
// waves finished GEMM2 (akl reads) and wsum reads before overwrite.
// ---------------------------------------------------------------------------
template <bool PARTIAL>
__global__ __launch_bounds__(256, 2) void netvlad_main(
    const float* __restrict__ xg, const float* __restrict__ wg,
    float* __restrict__ Sg, float* __restrict__ Ag) {
  __shared__ __align__(16) u16 x_ld[SUB * XLD_S];       // [l][d], cross-wave
  __shared__ __align__(16) u16 x_dl[4][64 * XDL_S];     // [w][d_local][l], wave-private
  __shared__ __align__(16) u16 akl[KK * AKL_S];         // bf16(e * rno)
  __shared__ float pnw[4][SUB];                         // per-wave norm partials
  __shared__ float wsum[4][SUB];                        // per-wave softmax partials

  const int tid  = threadIdx.x;
  const int w    = tid >> 6;
  const int lane = tid & 63;
  const int quad = lane >> 4;
  const int l15  = lane & 15;
  const int g    = lane >> 3;       // 0..7: row-group within wave's 64 rows
  const int c    = lane & 7;        // 0..7: 4-col group within the 32 cols
  const int n    = blockIdx.x >> 3;
  const int ch   = blockIdx.x & 7;

  // W fragments: wave w owns k-tile w for GEMM1. A-frag: A[m=l15][kred=quad*8+j]
  bf16x8 aw[8];
  {
    const float* wp = wg + (w * 16 + l15) * DD + quad * 8;
#pragma unroll
    for (int s = 0; s < 8; ++s) {
      f32x4 wa = *(const f32x4*)(wp + s * 32);
      f32x4 wb = *(const f32x4*)(wp + s * 32 + 4);
      bf16x8 t;
#pragma unroll
      for (int j = 0; j < 4; ++j) { t[j] = (short)f2bf(wa[j]); t[j + 4] = (short)f2bf(wb[j]); }
      aw[s] = t;
    }
  }

  f32x4 acc2[4][4];                 // [kt][dt]: k = kt*16+quad*4+r, d = w*64+dt*16+l15
#pragma unroll
  for (int a = 0; a < 4; ++a)
#pragma unroll
    for (int b = 0; b < 4; ++b) acc2[a][b] = (f32x4){0.f, 0.f, 0.f, 0.f};
  float regAk[4] = {0.f, 0.f, 0.f, 0.f};

  // thread's global base: rows w*64+g*8 .. +7 (via +i*LL), cols c*4..+3
  const float* xw = xg + (size_t)n * DD * LL + (size_t)(w * 64 + g * 8) * LL
                    + ch * CHUNK + c * 4;

  f32x4 buf0[8], buf1[8];
  // preload substep 0
#pragma unroll
  for (int i = 0; i < 8; ++i) buf0[i] = *(const f32x4*)(xw + (size_t)i * LL);

  auto step = [&](f32x4 (&cur)[8], f32x4 (&nxt)[8], int s) {
    // ---- prefetch substep s+1 (stays in flight across all barriers)
    if (s + 1 < NSTEP) {
      const float* q = xw + (s + 1) * SUB;
#pragma unroll
      for (int i = 0; i < 8; ++i) nxt[i] = *(const f32x4*)(q + (size_t)i * LL);
    }

    // ---- norms: wave sums its 64 d-rows per column
    {
      f32x4 pj = (f32x4){0.f, 0.f, 0.f, 0.f};
#pragma unroll
      for (int i = 0; i < 8; ++i) pj += cur[i] * cur[i];
#pragma unroll
      for (int o = 8; o <= 32; o <<= 1)
#pragma unroll
        for (int j = 0; j < 4; ++j) pj[j] += __shfl_xor(pj[j], o);
      if (g == 0) *(f32x4*)&pnw[w][c * 4] = pj;
    }

    // ---- convert to bf16 (unscaled), stage x_ld only
    {
      u16 xb[8][4];
#pragma unroll
      for (int i = 0; i < 8; ++i)
#pragma unroll
        for (int j = 0; j < 4; ++j) xb[i][j] = f2bf(cur[i][j]);
#pragma unroll
      for (int j = 0; j < 4; ++j) {     // x_ld: row c*4+j, d-offset w*64+g*8 (b128)
        bf16x8 col;
#pragma unroll
        for (int i = 0; i < 8; ++i) col[i] = (short)xb[i][j];
        *(bf16x8*)&x_ld[(c * 4 + j) * XLD_S + w * 64 + g * 8] = col;
      }
    }
    barrier_lds();   // B1: x_ld + pnw ready

    // ---- GEMM1: logits 16k x 32l, K=256 over d
    f32x4 acc1[2];
    acc1[0] = (f32x4){0.f, 0.f, 0.f, 0.f};
    acc1[1] = (f32x4){0.f, 0.f, 0.f, 0.f};
#pragma unroll
    for (int s8 = 0; s8 < 8; ++s8)
#pragma unroll
      for (int lt = 0; lt < 2; ++lt) {
        bf16x8 b = *(const bf16x8*)&x_ld[(lt * 16 + l15) * XLD_S + s8 * 32 + quad * 8];
        acc1[lt] = __builtin_amdgcn_mfma_f32_16x16x32_bf16(aw[s8], b, acc1[lt], 0, 0, 0);
      }
    // softmax p1: scale by rno, exp, per-wave k-sums, write akl = bf16(e*rno)
    float e[2][4], ps[2];
#pragma unroll
    for (int lt = 0; lt < 2; ++lt) {
      int col = lt * 16 + l15;
      float s4 = pnw[0][col] + pnw[1][col] + pnw[2][col] + pnw[3][col];
      float rno = rsqrtf(fmaxf(s4, 1e-24f));
      float p = 0.f;
#pragma unroll
      for (int r = 0; r < 4; ++r) { e[lt][r] = __expf(acc1[lt][r] * rno); p += e[lt][r]; }
      p += __shfl_xor(p, 16);
      p += __shfl_xor(p, 32);
      ps[lt] = p;
#pragma unroll
      for (int r = 0; r < 4; ++r)
        akl[(w * 16 + quad * 4 + r) * AKL_S + col] = f2bf(e[lt][r] * rno);
    }
    if (quad < 2) wsum[w][quad * 16 + l15] = (quad == 0) ? ps[0] : ps[1];
    barrier_lds();   // B2: wsum + akl ready; all GEMM1 x_ld/pnw reads done

    // ---- post-B2: rs per column, A accumulation, wave-private x_dl = x*rs
#pragma unroll
    for (int lt = 0; lt < 2; ++lt) {
      int col = lt * 16 + l15;
      float rs = 1.f / (wsum[0][col] + wsum[1][col] + wsum[2][col] + wsum[3][col]);
#pragma unroll
      for (int r = 0; r < 4; ++r) regAk[r] += e[lt][r] * rs;
    }
    {
      f32x4 den = *(const f32x4*)&wsum[0][c * 4];
      den += *(const f32x4*)&wsum[1][c * 4];
      den += *(const f32x4*)&wsum[2][c * 4];
      den += *(const f32x4*)&wsum[3][c * 4];
      f32x4 rs4;
#pragma unroll
      for (int j = 0; j < 4; ++j) rs4[j] = 1.f / den[j];
#pragma unroll
      for (int i = 0; i < 8; ++i) {   // x_dl: row g*8+i, cols c*4..+3 (b64)
        u32 lo = (u32)f2bf(cur[i][0] * rs4[0]) | ((u32)f2bf(cur[i][1] * rs4[1]) << 16);
        u32 hi = (u32)f2bf(cur[i][2] * rs4[2]) | ((u32)f2bf(cur[i][3] * rs4[3]) << 16);
        *(uint2*)&x_dl[w][(g * 8 + i) * XDL_S + c * 4] = make_uint2(lo, hi);
      }
    }
    // wave-private write->read: LDS ordering only, no s_barrier needed
    asm volatile("s_waitcnt lgkmcnt(0)" ::: "memory");

    // ---- GEMM2: all 64 k x own 64 d, K=32 cols
    bf16x8 bx[4];
#pragma unroll
    for (int dt = 0; dt < 4; ++dt)
      bx[dt] = *(const bf16x8*)&x_dl[w][(dt * 16 + l15) * XDL_S + quad * 8];
#pragma unroll
    for (int kt = 0; kt < 4; ++kt) {
      bf16x8 aA = *(const bf16x8*)&akl[(kt * 16 + l15) * AKL_S + quad * 8];
#pragma unroll
      for (int dt = 0; dt < 4; ++dt)
        acc2[kt][dt] = __builtin_amdgcn_mfma_f32_16x16x32_bf16(aA, bx[dt], acc2[kt][dt], 0, 0, 0);
    }
    // no trailing barrier: next substep's stage writes (x_ld/pnw) are safe
    // because this wave passed B2 (all waves' GEMM1 reads complete), and
    // akl/wsum overwrites happen only after the NEXT B1.
  };

#pragma unroll 1
  for (int sp = 0; sp < NSTEP / 2; ++sp) {
    step(buf0, buf1, 2 * sp);
    step(buf1, buf0, 2 * sp + 1);
  }

  // ---- epilogue
  if (PARTIAL) {
    float* Sp = Sg + (size_t)blockIdx.x * SSZ;
#pragma unroll
    for (int kt = 0; kt < 4; ++kt)
#pragma unroll
      for (int dt = 0; dt < 4; ++dt)
#pragma unroll
        for (int r = 0; r < 4; ++r)
          Sp[(kt * 16 + quad * 4 + r) * DD + w * 64 + dt * 16 + l15] = acc2[kt][dt][r];
  } else {
    float* Sn = Sg + (size_t)n * SSZ;
#pragma unroll
    for (int kt = 0; kt < 4; ++kt)
#pragma unroll
      for (int dt = 0; dt < 4; ++dt)
#pragma unroll
        for (int r = 0; r < 4; ++r)
          atomicAdd(&Sn[(kt * 16 + quad * 4 + r) * DD + w * 64 + dt * 16 + l15],
                    acc2[kt][dt][r]);
  }
#pragma unroll
  for (int o = 1; o <= 8; o <<= 1)
#pragma unroll
    for (int r = 0; r < 4; ++r) regAk[r] += __shfl_xor(regAk[r], o);
  if (l15 == 0) {
    if (PARTIAL) {
      float* Ap = Ag + (size_t)blockIdx.x * KK;
#pragma unroll
      for (int r = 0; r < 4; ++r) Ap[w * 16 + quad * 4 + r] = regAk[r];
    } else {
#pragma unroll
      for (int r = 0; r < 4; ++r) atomicAdd(&Ag[n * KK + w * 16 + quad * 4 + r], regAk[r]);
    }
  }
}

// ---------------------------------------------------------------------------
// Finalize: sum NSL slices, subtract A*c, intra-norm, global norm, store.
// One block per n, 1024 threads (16 waves): wave w -> k = w*4+i. 4x the waves
// of the previous 256-thread version: only 64 CUs are active (64 blocks), so
// per-CU memory-level parallelism is what saturates HBM here.
// ---------------------------------------------------------------------------
template <int NSL>
__global__ __launch_bounds__(1024, 1) void netvlad_fin(
    const float* __restrict__ Sg, const float* __restrict__ Ag,
    const float* __restrict__ cg, float* __restrict__ outg) {
  __shared__ float wtot[16];
  const int n = blockIdx.x, tid = threadIdx.x;
  const int w = tid >> 6, lane = tid & 63;
  const float* Sb = Sg + (size_t)n * NSL * SSZ;
  const float* Ab = Ag + (size_t)n * NSL * KK;

  f32x4 v[4];
  float rk[4];
  float tot = 0.f;
#pragma unroll
  for (int i = 0; i < 4; ++i) {
    const int k = w * 4 + i;
    float Ak = 0.f;
#pragma unroll
    for (int sl = 0; sl < NSL; ++sl) Ak += Ab[sl * KK + k];
    f32x4 sacc = (f32x4){0.f, 0.f, 0.f, 0.f};
#pragma unroll
    for (int sl = 0; sl < NSL; ++sl)
      sacc += *(const f32x4*)&Sb[(size_t)sl * SSZ + k * DD + lane * 4];
    f32x4 c4 = *(const f32x4*)&cg[k * DD + lane * 4];
    f32x4 t = sacc - Ak * c4;
    v[i] = t;
    float q = t[0] * t[0] + t[1] * t[1] + t[2] * t[2] + t[3] * t[3];
#pragma unroll
    for (int o = 1; o <= 32; o <<= 1) q += __shfl_xor(q, o);
    float r = 1.f / fmaxf(sqrtf(q), 1e-12f);
    rk[i] = r;
    tot += q * r * r;
  }
  if (lane == 0) wtot[w] = tot;
  __syncthreads();
  float gtot = 0.f;
#pragma unroll
  for (int u = 0; u < 16; ++u) gtot += wtot[u];
  const float gs = 1.f / fmaxf(sqrtf(gtot), 1e-12f);
#pragma unroll
  for (int i = 0; i < 4; ++i) {
    const int k = w * 4 + i;
    const float sc = rk[i] * gs;
    f32x4 o = v[i];
    o[0] *= sc; o[1] *= sc; o[2] *= sc; o[3] *= sc;
    *(f32x4*)&outg[(size_t)n * SSZ + k * DD + lane * 4] = o;
  }
}

extern "C" void kernel_launch(void* const* d_in, const int* in_sizes, int n_in,
                              void* d_out, int out_size, void* d_ws, size_t ws_size,
                              hipStream_t stream) {
  const float* x   = (const float*)d_in[0];
  const float* wgt = (const float*)d_in[1];
  const float* cen = (const float*)d_in[2];
  float* out = (float*)d_out;

  const size_t nblk = (size_t)NN * NCH;                      // 512
  const size_t need = nblk * SSZ * 4 + nblk * KK * 4;        // ~33.7 MB
  if (ws_size >= need) {
    float* Sp = (float*)d_ws;
    float* Ap = Sp + nblk * SSZ;
    hipLaunchKernelGGL((netvlad_main<true>), dim3(NN * NCH), dim3(256), 0, stream, x, wgt, Sp, Ap);
    hipLaunchKernelGGL((netvlad_fin<NCH>), dim3(NN), dim3(1024), 0, stream, Sp, Ap, cen, out);
  } else {
    float* S = (float*)d_ws;
    float* A = S + (size_t)NN * SSZ;
    const int n4 = (NN * SSZ + NN * KK) / 4;
    hipLaunchKernelGGL(zero_ws_kernel, dim3((n4 + 255) / 256), dim3(256), 0, stream, S, n4);
    hipLaunchKernelGGL((netvlad_main<false>), dim3(NN * NCH), dim3(256), 0, stream, x, wgt, S, A);
    hipLaunchKernelGGL((netvlad_fin<1>), dim3(NN), dim3(1024), 0, stream, S, A, cen, out);
  }
}